// Round 3
// baseline (13550.835 us; speedup 1.0000x reference)
//
#include <hip/hip_runtime.h>

#define NB 1024
#define SL 300
#define NT 150
#define NH 256
#define LA 320
#define NV 81

// workspace float offsets
#define OFF_WATT    0u        // [512][320] W_att^T
#define OFF_WCOMBT  163840u   // [512][256] W_comb^T
#define OFF_P1B     294912u   // [81][320]  emb@W_att[:, :256]^T + b_att
#define OFF_P2B     320832u   // [81][256]  emb@W_comb[:, :256]^T + b_comb
#define OFF_Q2T     341568u   // [81][256]  emb@W_comb[:, 256:]^T
#define OFF_Q2PE    362304u   // [256]      pe@W_comb[:, 256:]^T
#define OFF_PE      362560u   // [256]
#define OFF_WCATP   362816u   // [512][1024] gate-interleaved cat(W_ih,W_hh)^T
#define OFF_BSUM    887104u   // [1024]     gate-interleaved b_ih+b_hh
#define OFF_WFCT    888128u   // [256][81]  W_fc^T
#define OFF_LOSS    908864u   // [1024]

static __device__ __forceinline__ float rcpf(float x)  { return __builtin_amdgcn_rcpf(x); }
static __device__ __forceinline__ float sigm(float x)  { return rcpf(1.f + __expf(-x)); }
static __device__ __forceinline__ float tanhf_(float x){ return 1.f - 2.f * rcpf(1.f + __expf(2.f * x)); }

// ---------------- setup kernels (one-time, cheap) ----------------
__global__ __launch_bounds__(128) void k_pe(float* __restrict__ pe) {
    const int i = threadIdx.x;                     // 0..127
    const float arg  = (float)(2 * i) * (-0.035977892078031968f);
    const float divf = expf(arg) * 300.0f;
    pe[2 * i]     = (float)sin((double)divf);
    pe[2 * i + 1] = (float)cos((double)divf);
}
__global__ __launch_bounds__(256) void k_tr_att(const float* __restrict__ W, float* __restrict__ WT) {
    const int i = blockIdx.x * 256 + threadIdx.x;
    if (i < 512 * LA) { const int k = i / LA, l = i - k * LA; WT[i] = W[l * 512 + k]; }
}
__global__ __launch_bounds__(256) void k_tr_comb(const float* __restrict__ W, float* __restrict__ WT) {
    const int i = blockIdx.x * 256 + threadIdx.x;
    const int k = i >> 8, j = i & 255;
    if (i < 512 * NH) WT[i] = W[j * 512 + k];
}
__global__ __launch_bounds__(320) void k_p1b(const float* __restrict__ emb, const float* __restrict__ WATT,
                                             const float* __restrict__ b_att, float* __restrict__ P1B) {
    __shared__ float e[NH];
    const int v = blockIdx.x, tid = threadIdx.x;
    if (tid < NH) e[tid] = emb[v * NH + tid];
    __syncthreads();
    float a = b_att[tid];
    #pragma unroll 8
    for (int k = 0; k < NH; ++k) a += e[k] * WATT[k * LA + tid];
    P1B[v * LA + tid] = a;
}
__global__ __launch_bounds__(256) void k_p2q(const float* __restrict__ emb, const float* __restrict__ WCOMBT,
                                             const float* __restrict__ b_comb,
                                             float* __restrict__ P2B, float* __restrict__ Q2T) {
    __shared__ float e[NH];
    const int v = blockIdx.x, tid = threadIdx.x;
    e[tid] = emb[v * NH + tid];
    __syncthreads();
    float a = b_comb[tid], q = 0.f;
    #pragma unroll 8
    for (int k = 0; k < NH; ++k) {
        a += e[k] * WCOMBT[k * NH + tid];
        q += e[k] * WCOMBT[(NH + k) * NH + tid];
    }
    P2B[v * NH + tid] = a;
    Q2T[v * NH + tid] = q;
}
__global__ __launch_bounds__(256) void k_q2pe(const float* __restrict__ pe, const float* __restrict__ WCOMBT,
                                              float* __restrict__ Q2PE) {
    __shared__ float e[NH];
    const int tid = threadIdx.x;
    e[tid] = pe[tid];
    __syncthreads();
    float q = 0.f;
    #pragma unroll 8
    for (int k = 0; k < NH; ++k) q += e[k] * WCOMBT[(NH + k) * NH + tid];
    Q2PE[tid] = q;
}
__global__ __launch_bounds__(256) void k_wcatp(const float* __restrict__ Wih, const float* __restrict__ Whh,
                                               float* __restrict__ WCATP) {
    const int i = blockIdx.x * 256 + threadIdx.x;
    if (i < 512 * 1024) {
        const int k = i >> 10, q = i & 1023, j = q >> 2, g = q & 3;
        WCATP[i] = (k < NH) ? Wih[(g * NH + j) * NH + k] : Whh[(g * NH + j) * NH + (k - NH)];
    }
}
__global__ __launch_bounds__(256) void k_bsum(const float* __restrict__ bih, const float* __restrict__ bhh,
                                              float* __restrict__ BSUM) {
    const int i = blockIdx.x * 256 + threadIdx.x;
    if (i < 1024) { const int j = i >> 2, g = i & 3; BSUM[i] = bih[g * NH + j] + bhh[g * NH + j]; }
}
__global__ __launch_bounds__(256) void k_trfc(const float* __restrict__ W, float* __restrict__ WT) {
    const int v = blockIdx.x, k = threadIdx.x;
    WT[k * NV + v] = W[v * NH + k];
}

// ---------------- the persistent decoder kernel ----------------
// grid 256 blocks x 512 threads; block owns 4 batch rows; whole t-loop inside.
__global__ __launch_bounds__(512) void k_run(
    const int* __restrict__ enc, const int* __restrict__ tgt,
    const float* __restrict__ WATT_H, const float* __restrict__ P1B,
    const float* __restrict__ P2B, const float* __restrict__ Q2T,
    const float* __restrict__ Q2PE, const float* __restrict__ WCATP,
    const float* __restrict__ BSUM, const float* __restrict__ WFCT,
    const float* __restrict__ b_fc, float* __restrict__ out_logits,
    float* __restrict__ loss_out)
{
    __shared__ float hbuf[2][4][NH];
    __shared__ float x_s[4][NH];
    __shared__ float p_s[4][LA];
    __shared__ float cw_s[4][NV];
    __shared__ float lg_s[4][96];
    __shared__ unsigned short idx16[4][SL];
    __shared__ unsigned short cnt16[4][NV];
    __shared__ unsigned short offs16[4][NV + 1];
    __shared__ float redM[4][2];
    __shared__ float redS[4][2][2];
    __shared__ float bfc_s[NV];
    __shared__ float loss_s[4];
    __shared__ int   xd_s[4];

    const int tid  = threadIdx.x;
    const int row  = tid >> 7;
    const int p    = tid & 127;
    const int wid  = tid >> 6;
    const int lane = tid & 63;
    const int whalf = wid & 1;
    const int row0 = blockIdx.x * 4;
    const int grow = row0 + row;

    // ---- init: zero h0, SOS token, counting-sort enc into per-vocab index lists ----
    for (int i = tid; i < 4 * NH; i += 512) hbuf[0][i >> 8][i & 255] = 0.f;
    if (tid < 4) { xd_s[tid] = 1; loss_s[tid] = 0.f; }
    if (tid < NV) bfc_s[tid] = b_fc[tid];
    const int* __restrict__ encr = enc + grow * SL;
    if (p < NV) {
        int c = 0;
        for (int l = 0; l < SL; ++l) c += (encr[l] == p);
        cnt16[row][p] = (unsigned short)c;
    }
    __syncthreads();
    if (p == 0) {
        int o = 0;
        offs16[row][0] = 0;
        for (int v = 0; v < NV; ++v) { o += cnt16[row][v]; offs16[row][v + 1] = (unsigned short)o; }
    }
    __syncthreads();
    if (p < NV) {
        int o = offs16[row][p];
        for (int l = 0; l < SL; ++l) if (encr[l] == p) idx16[row][o++] = (unsigned short)l;
    }
    __syncthreads();

    float creg0 = 0.f, creg1 = 0.f;       // cell state, lives in registers for all 150 steps
    const int u0 = 2 * p, u1 = 2 * p + 1;

    for (int t = 0; t < NT; ++t) {
        const int pb = t & 1;
        const float* __restrict__ hrow = hbuf[pb][row];
        const int xv = xd_s[row];

        // ---- phase 1: attention logits z (3 l's per thread) + softmax stats ----
        const int l0 = p, l1 = p + 128, l2 = 256 + (p & 63);
        const bool has2 = (p < 64);
        const float* __restrict__ P1r = P1B + xv * LA;
        float z0 = P1r[l0], z1 = P1r[l1], z2 = P1r[l2];
        #pragma unroll 4
        for (int kb = 0; kb < NH / 4; ++kb) {
            const float4 h4 = *(const float4*)(hrow + kb * 4);
            const float* __restrict__ wr = WATT_H + kb * 4 * LA;
            z0 += h4.x * wr[l0];          z1 += h4.x * wr[l1];          z2 += h4.x * wr[l2];
            z0 += h4.y * wr[LA + l0];     z1 += h4.y * wr[LA + l1];     z2 += h4.y * wr[LA + l2];
            z0 += h4.z * wr[2 * LA + l0]; z1 += h4.z * wr[2 * LA + l1]; z2 += h4.z * wr[2 * LA + l2];
            z0 += h4.w * wr[3 * LA + l0]; z1 += h4.w * wr[3 * LA + l1]; z2 += h4.w * wr[3 * LA + l2];
        }
        float m = fmaxf(z0, z1);
        if (has2) m = fmaxf(m, z2);
        #pragma unroll
        for (int off = 32; off > 0; off >>= 1) m = fmaxf(m, __shfl_xor(m, off));
        if (lane == 0) redM[row][whalf] = m;
        __syncthreads();                                   // S1
        const float M = fmaxf(redM[row][0], redM[row][1]);
        const float e0 = __expf(z0 - M), e1 = __expf(z1 - M);
        const float e2 = has2 ? __expf(z2 - M) : 0.f;
        p_s[row][l0] = e0; p_s[row][l1] = e1;
        if (has2) p_s[row][l2] = e2;
        float sa = e0 + e1 + e2;
        float sh = (has2 && p >= 44) ? e2 : 0.f;           // l in [300,320)
        #pragma unroll
        for (int off = 32; off > 0; off >>= 1) { sa += __shfl_xor(sa, off); sh += __shfl_xor(sh, off); }
        if (lane == 0) { redS[row][whalf][0] = sa; redS[row][whalf][1] = sh; }
        __syncthreads();                                   // S2

        // vocab binning via precomputed index lists (deterministic)
        if (p < NV) {
            const int o0 = offs16[row][p], o1 = offs16[row][p + 1];
            float s = 0.f;
            for (int o = o0; o < o1; ++o) s += p_s[row][idx16[row][o]];
            cw_s[row][p] = s;
        }
        __syncthreads();                                   // S3

        // ---- phase 2: x = relu(P2b[xv] + (Q2T^T cw + S300*q2pe)/S_all) ----
        {
            const float SA   = redS[row][0][0] + redS[row][1][0];
            const float SHI  = redS[row][0][1] + redS[row][1][1];
            const float inv  = 1.0f / SA;
            const float s300 = SA - SHI;
            const int j0 = p, j1 = p + 128;
            float a0 = s300 * Q2PE[j0], a1 = s300 * Q2PE[j1];
            #pragma unroll 4
            for (int v = 0; v < NV; ++v) {
                const float cv = cw_s[row][v];
                a0 += cv * Q2T[v * NH + j0];
                a1 += cv * Q2T[v * NH + j1];
            }
            const float* __restrict__ P2r = P2B + xv * NH;
            x_s[row][j0] = fmaxf(P2r[j0] + a0 * inv, 0.f);
            x_s[row][j1] = fmaxf(P2r[j1] + a1 * inv, 0.f);
        }
        __syncthreads();                                   // S4

        // ---- phase 3: gates GEMM (thread = 2 hidden units x 4 gates) + LSTM ----
        float4 acc0, acc1;
        {
            acc0 = *(const float4*)(BSUM + 8 * p);
            acc1 = *(const float4*)(BSUM + 8 * p + 4);
            const float* __restrict__ Bp  = WCATP + 8 * p;              // x-half rows 0..255
            const float* __restrict__ Bph = WCATP + 256 * 1024 + 8 * p; // h-half rows 256..511
            const float* __restrict__ A0 = x_s[row];
#define GSTEP(base, aval, kidx) { \
            const float4 b0 = *(const float4*)((base) + (size_t)(kidx) * 1024);     \
            const float4 b1 = *(const float4*)((base) + (size_t)(kidx) * 1024 + 4); \
            acc0.x += (aval) * b0.x; acc0.y += (aval) * b0.y;           \
            acc0.z += (aval) * b0.z; acc0.w += (aval) * b0.w;           \
            acc1.x += (aval) * b1.x; acc1.y += (aval) * b1.y;           \
            acc1.z += (aval) * b1.z; acc1.w += (aval) * b1.w; }
            #pragma unroll 2
            for (int kb = 0; kb < 64; ++kb) {
                const float4 a4 = *(const float4*)(A0 + kb * 4);
                GSTEP(Bp, a4.x, kb * 4 + 0) GSTEP(Bp, a4.y, kb * 4 + 1)
                GSTEP(Bp, a4.z, kb * 4 + 2) GSTEP(Bp, a4.w, kb * 4 + 3)
            }
            #pragma unroll 2
            for (int kb = 0; kb < 64; ++kb) {
                const float4 a4 = *(const float4*)(hrow + kb * 4);
                GSTEP(Bph, a4.x, kb * 4 + 0) GSTEP(Bph, a4.y, kb * 4 + 1)
                GSTEP(Bph, a4.z, kb * 4 + 2) GSTEP(Bph, a4.w, kb * 4 + 3)
            }
#undef GSTEP
            // epilogue: acc = (i,f,g,o) per unit
            creg0 = sigm(acc0.y) * creg0 + sigm(acc0.x) * tanhf_(acc0.z);
            hbuf[pb ^ 1][row][u0] = sigm(acc0.w) * tanhf_(creg0);
            creg1 = sigm(acc1.y) * creg1 + sigm(acc1.x) * tanhf_(acc1.z);
            hbuf[pb ^ 1][row][u1] = sigm(acc1.w) * tanhf_(creg1);
        }
        __syncthreads();                                   // S5

        // ---- phase 4: fc logits + output write ----
        if (p < NV) {
            const float* __restrict__ h2 = hbuf[pb ^ 1][row];
            const float* __restrict__ Wc = WFCT + p;
            float acc = bfc_s[p];
            #pragma unroll 4
            for (int kb = 0; kb < 64; ++kb) {
                const float4 h4 = *(const float4*)(h2 + kb * 4);
                acc += h4.x * Wc[(kb * 4 + 0) * NV] + h4.y * Wc[(kb * 4 + 1) * NV]
                     + h4.z * Wc[(kb * 4 + 2) * NV] + h4.w * Wc[(kb * 4 + 3) * NV];
            }
            lg_s[row][p] = acc;
            out_logits[(size_t)(t * NB + grow) * NV + p] = acc;
        }
        __syncthreads();                                   // S6

        // ---- per-row argmax (first-max) + log-softmax loss, one wave per row ----
        if (wid < 4) {
            const int r = wid;
            float v0 = (lane < NV) ? lg_s[r][lane] : -3.4e38f;
            int   i0 = lane;
            if (lane < NV - 64) {
                const float vb = lg_s[r][64 + lane];
                if (vb > v0) { v0 = vb; i0 = 64 + lane; }
            }
            #pragma unroll
            for (int off = 32; off > 0; off >>= 1) {
                const float vo = __shfl_xor(v0, off);
                const int   io = __shfl_xor(i0, off);
                if (vo > v0 || (vo == v0 && io < i0)) { v0 = vo; i0 = io; }
            }
            float e = (lane < NV) ? __expf(lg_s[r][lane] - v0) : 0.f;
            if (lane < NV - 64) e += __expf(lg_s[r][64 + lane] - v0);
            #pragma unroll
            for (int off = 32; off > 0; off >>= 1) e += __shfl_xor(e, off);
            if (lane == 0) {
                const int y = tgt[(row0 + r) * NT + t];
                loss_s[r] += -(lg_s[r][y] - v0 - logf(e));
                xd_s[r] = i0;
            }
        }
        __syncthreads();                                   // S7
    }

    if (tid < 4) loss_out[row0 + tid] = loss_s[tid];
}

// ---------------- final mean ----------------
__global__ __launch_bounds__(256) void k_final(const float* __restrict__ loss, float* __restrict__ dst) {
    const int tid = threadIdx.x;
    float v = loss[tid] + loss[tid + 256] + loss[tid + 512] + loss[tid + 768];
    #pragma unroll
    for (int o = 32; o > 0; o >>= 1) v += __shfl_xor(v, o);
    __shared__ float red[4];
    if ((tid & 63) == 0) red[tid >> 6] = v;
    __syncthreads();
    if (tid == 0) dst[0] = (red[0] + red[1] + red[2] + red[3]) / (float)(NB * NT);
}

extern "C" void kernel_launch(void* const* d_in, const int* in_sizes, int n_in,
                              void* d_out, int out_size, void* d_ws, size_t ws_size,
                              hipStream_t stream) {
    const int*   enc    = (const int*)d_in[0];
    const int*   tgt    = (const int*)d_in[1];
    const float* emb    = (const float*)d_in[3];
    const float* W_att  = (const float*)d_in[4];
    const float* b_att  = (const float*)d_in[5];
    const float* W_comb = (const float*)d_in[6];
    const float* b_comb = (const float*)d_in[7];
    const float* W_ih   = (const float*)d_in[8];
    const float* b_ih   = (const float*)d_in[9];
    const float* W_hh   = (const float*)d_in[10];
    const float* b_hh   = (const float*)d_in[11];
    const float* W_fc   = (const float*)d_in[12];
    const float* b_fc   = (const float*)d_in[13];

    float* ws  = (float*)d_ws;
    float* out = (float*)d_out;

    hipLaunchKernelGGL(k_pe,      dim3(1),    dim3(128), 0, stream, ws + OFF_PE);
    hipLaunchKernelGGL(k_tr_att,  dim3(640),  dim3(256), 0, stream, W_att,  ws + OFF_WATT);
    hipLaunchKernelGGL(k_tr_comb, dim3(512),  dim3(256), 0, stream, W_comb, ws + OFF_WCOMBT);
    hipLaunchKernelGGL(k_p1b,     dim3(81),   dim3(320), 0, stream, emb, ws + OFF_WATT, b_att, ws + OFF_P1B);
    hipLaunchKernelGGL(k_p2q,     dim3(81),   dim3(256), 0, stream, emb, ws + OFF_WCOMBT, b_comb,
                       ws + OFF_P2B, ws + OFF_Q2T);
    hipLaunchKernelGGL(k_q2pe,    dim3(1),    dim3(256), 0, stream, ws + OFF_PE, ws + OFF_WCOMBT, ws + OFF_Q2PE);
    hipLaunchKernelGGL(k_wcatp,   dim3(2048), dim3(256), 0, stream, W_ih, W_hh, ws + OFF_WCATP);
    hipLaunchKernelGGL(k_bsum,    dim3(4),    dim3(256), 0, stream, b_ih, b_hh, ws + OFF_BSUM);
    hipLaunchKernelGGL(k_trfc,    dim3(81),   dim3(256), 0, stream, W_fc, ws + OFF_WFCT);

    hipLaunchKernelGGL(k_run, dim3(256), dim3(512), 0, stream,
                       enc, tgt,
                       ws + OFF_WATT + 256u * LA,   // h-half of W_att^T
                       ws + OFF_P1B, ws + OFF_P2B, ws + OFF_Q2T, ws + OFF_Q2PE,
                       ws + OFF_WCATP, ws + OFF_BSUM, ws + OFF_WFCT, b_fc,
                       out, ws + OFF_LOSS);

    hipLaunchKernelGGL(k_final, dim3(1), dim3(256), 0, stream, ws + OFF_LOSS, out + (out_size - 1));
}

// Round 4
// 7566.690 us; speedup vs baseline: 1.7909x; 1.7909x over previous
//
#include <hip/hip_runtime.h>

#define NB 1024
#define SL 300
#define NT 150
#define NH 256
#define LA 320
#define NV 81

// ws float offsets
#define OFF_WATT    0u         // [512][320] full W_att^T (setup intermediate)
#define OFF_WCOMBT  163840u    // [512][256] W_comb^T (setup intermediate)
#define OFF_P1B     294912u    // [81][320]  emb@W_att[:,:256]^T + b_att
#define OFF_P2B     320832u    // [81][256]  emb@W_comb[:,:256]^T + b_comb
#define OFF_Q2T     341568u    // [81][256]  emb@W_comb[:,256:]^T (intermediate)
#define OFF_Q2PE    362304u    // [256]      pe@W_comb[:,256:]^T
#define OFF_PE      362560u    // [256]
#define OFF_WCATPT  362816u    // [128][4096] 4k-panel gates weights, col=(j*4+g)
#define OFF_WATTP   887104u    // [64][1280]  4k-panel h-half W_att^T
#define OFF_Q2TP    969024u    // [21][1024]  4v-panel Q2T
#define OFF_WFCTP   990528u    // [64][324]   4k-panel W_fc^T
#define OFF_LOSS    1011264u   // [1024]

static __device__ __forceinline__ float rcpf(float x)  { return __builtin_amdgcn_rcpf(x); }
static __device__ __forceinline__ float sigm(float x)  { return rcpf(1.f + __expf(-x)); }
static __device__ __forceinline__ float tanhf_(float x){ return 1.f - 2.f * rcpf(1.f + __expf(2.f * x)); }

// ---------------- setup kernels ----------------
__global__ __launch_bounds__(128) void k_pe(float* __restrict__ pe) {
    const int i = threadIdx.x;
    const float arg  = (float)(2 * i) * (-0.035977892078031968f);
    const float divf = expf(arg) * 300.0f;
    pe[2 * i]     = (float)sin((double)divf);
    pe[2 * i + 1] = (float)cos((double)divf);
}
__global__ __launch_bounds__(256) void k_tr_att(const float* __restrict__ W, float* __restrict__ WT) {
    const int i = blockIdx.x * 256 + threadIdx.x;
    if (i < 512 * LA) { const int k = i / LA, l = i - k * LA; WT[i] = W[l * 512 + k]; }
}
__global__ __launch_bounds__(256) void k_tr_comb(const float* __restrict__ W, float* __restrict__ WT) {
    const int i = blockIdx.x * 256 + threadIdx.x;
    const int k = i >> 8, j = i & 255;
    if (i < 512 * NH) WT[i] = W[j * 512 + k];
}
__global__ __launch_bounds__(320) void k_p1b(const float* __restrict__ emb, const float* __restrict__ WATT,
                                             const float* __restrict__ b_att, float* __restrict__ P1B) {
    __shared__ float e[NH];
    const int v = blockIdx.x, tid = threadIdx.x;
    if (tid < NH) e[tid] = emb[v * NH + tid];
    __syncthreads();
    float a = b_att[tid];
    #pragma unroll 8
    for (int k = 0; k < NH; ++k) a += e[k] * WATT[k * LA + tid];
    P1B[v * LA + tid] = a;
}
__global__ __launch_bounds__(256) void k_p2q(const float* __restrict__ emb, const float* __restrict__ WCOMBT,
                                             const float* __restrict__ b_comb,
                                             float* __restrict__ P2B, float* __restrict__ Q2T) {
    __shared__ float e[NH];
    const int v = blockIdx.x, tid = threadIdx.x;
    e[tid] = emb[v * NH + tid];
    __syncthreads();
    float a = b_comb[tid], q = 0.f;
    #pragma unroll 8
    for (int k = 0; k < NH; ++k) {
        a += e[k] * WCOMBT[k * NH + tid];
        q += e[k] * WCOMBT[(NH + k) * NH + tid];
    }
    P2B[v * NH + tid] = a;
    Q2T[v * NH + tid] = q;
}
__global__ __launch_bounds__(256) void k_q2pe(const float* __restrict__ pe, const float* __restrict__ WCOMBT,
                                              float* __restrict__ Q2PE) {
    __shared__ float e[NH];
    const int tid = threadIdx.x;
    e[tid] = pe[tid];
    __syncthreads();
    float q = 0.f;
    #pragma unroll 8
    for (int k = 0; k < NH; ++k) q += e[k] * WCOMBT[(NH + k) * NH + tid];
    Q2PE[tid] = q;
}
// gates weights -> 4k panels: elem (k, c=(j*4+g)) at [(k>>2)*4096 + c*4 + (k&3)]
__global__ __launch_bounds__(256) void k_pan_cat(const float* __restrict__ Wih, const float* __restrict__ Whh,
                                                 float* __restrict__ P) {
    const int i = blockIdx.x * 256 + threadIdx.x;
    if (i < 512 * 1024) {
        const int k = i >> 10, c = i & 1023, j = c >> 2, g = c & 3;
        const float v = (k < NH) ? Wih[(g * NH + j) * NH + k] : Whh[(g * NH + j) * NH + (k - NH)];
        P[(k >> 2) * 4096 + c * 4 + (k & 3)] = v;
    }
}
// h-half W_att^T -> panels: elem (k in 0..255, l) at [(k>>2)*1280 + l*4 + (k&3)]
__global__ __launch_bounds__(256) void k_pan_att(const float* __restrict__ W, float* __restrict__ P) {
    const int i = blockIdx.x * 256 + threadIdx.x;
    if (i < 256 * LA) {
        const int k = i / LA, l = i - k * LA;
        P[(k >> 2) * 1280 + l * 4 + (k & 3)] = W[l * 512 + 256 + k];
    }
}
// Q2T -> 4v panels: elem (v, j) at [(v>>2)*1024 + j*4 + (v&3)]
__global__ __launch_bounds__(256) void k_pan_q2(const float* __restrict__ Q2T, float* __restrict__ P) {
    const int i = blockIdx.x * 256 + threadIdx.x;
    if (i < NV * NH) {
        const int v = i >> 8, j = i & 255;
        P[(v >> 2) * 1024 + j * 4 + (v & 3)] = Q2T[v * NH + j];
    }
}
// W_fc^T -> 4k panels of width 81: elem (k, v) at [(k>>2)*324 + v*4 + (k&3)]
__global__ __launch_bounds__(256) void k_pan_fc(const float* __restrict__ W, float* __restrict__ P) {
    const int i = blockIdx.x * 256 + threadIdx.x;
    if (i < 64 * 324) {
        const int panel = i / 324, off = i - panel * 324;
        const int v = off >> 2, kk = panel * 4 + (off & 3);
        P[i] = W[v * NH + kk];
    }
}

// ---------------- persistent decoder: 256 blocks x 1024 threads, 4 rows/block ----------------
__global__ __launch_bounds__(1024) void k_run(
    const int* __restrict__ enc, const int* __restrict__ tgt,
    const float* __restrict__ WATTP, const float* __restrict__ P1B,
    const float* __restrict__ P2B, const float* __restrict__ Q2TP,
    const float* __restrict__ Q2PE, const float* __restrict__ WCATPT,
    const float* __restrict__ WFCTP,
    const float* __restrict__ bih, const float* __restrict__ bhh,
    const float* __restrict__ bfc, float* __restrict__ out_logits,
    float* __restrict__ loss_out)
{
    __shared__ float hbuf[2][4][260];       // h double-buffer (pad 260 -> bank-shifted, 16B-aligned rows)
    __shared__ float x_s[4][260];
    __shared__ float p_s[4][LA];            // z then exp
    __shared__ float gex[4][1024];          // gate exchange
    __shared__ float bsum_lds[1024];
    __shared__ float cw_s[4][84];
    __shared__ float lg_s[4][84];
    __shared__ float lgpart[2][4][84];
    __shared__ unsigned short idx16[4][SL];
    __shared__ unsigned short cnt16[4][NV];
    __shared__ unsigned short offs16[4][NV + 1];
    __shared__ float redM[4][4];
    __shared__ float redS[4][4][2];
    __shared__ float bfc_s[84];
    __shared__ float loss_s[4];
    __shared__ int   xd_s[4];

    const int tid  = threadIdx.x;
    const int r4   = tid & 3;       // quad-row (weight-addr shared across quad)
    const int q4   = tid >> 2;      // 0..255
    const int rowg = tid >> 8;      // row-group for (r,j) phases
    const int jg   = tid & 255;
    const int wid  = tid >> 6;
    const int lane = tid & 63;
    const int row0 = blockIdx.x * 4;

    // ---- init ----
    for (int i = tid; i < 4 * 260; i += 1024) {
        const int rr = i / 260, kk = i - rr * 260;
        hbuf[0][rr][kk] = 0.f; hbuf[1][rr][kk] = 0.f; x_s[rr][kk] = 0.f;
    }
    { const int j = tid >> 2, g = tid & 3; bsum_lds[tid] = bih[g * NH + j] + bhh[g * NH + j]; }
    if (tid < 84) bfc_s[tid] = (tid < NV) ? bfc[tid] : 0.f;
    if (tid < 4 * 84) { cw_s[tid / 84][tid % 84] = 0.f; }
    if (tid < 4) { xd_s[tid] = 1; loss_s[tid] = 0.f; }
    const int* __restrict__ encr = enc + (row0 + rowg) * SL;
    if (jg < NV) {
        int c = 0;
        for (int l = 0; l < SL; ++l) c += (encr[l] == jg);
        cnt16[rowg][jg] = (unsigned short)c;
    }
    __syncthreads();
    if (jg == 0) {
        int o = 0; offs16[rowg][0] = 0;
        for (int v = 0; v < NV; ++v) { o += cnt16[rowg][v]; offs16[rowg][v + 1] = (unsigned short)o; }
    }
    __syncthreads();
    if (jg < NV) {
        int o = offs16[rowg][jg];
        for (int l = 0; l < SL; ++l) if (encr[l] == jg) idx16[rowg][o++] = (unsigned short)l;
    }
    __syncthreads();

    float creg = 0.f;   // cell state for (rowg, jg), in-register across all 150 steps

    for (int t = 0; t < NT; ++t) {
        const int pb = t & 1;

        // ---- phase 1: attention logits z ----
        {
            const int l = q4;
            const int xv = xd_s[r4];
            const float* __restrict__ hr = &hbuf[pb][r4][0];
            float z = P1B[xv * LA + l];
            const bool has2 = (tid < 256);
            const int l2 = 256 + q4;
            float z2 = has2 ? P1B[xv * LA + l2] : 0.f;
            #pragma unroll 4
            for (int kb = 0; kb < 64; ++kb) {
                const float4 w  = *(const float4*)(WATTP + kb * 1280 + l * 4);
                const float4 h4 = *(const float4*)(hr + kb * 4);
                z += w.x * h4.x + w.y * h4.y + w.z * h4.z + w.w * h4.w;
                if (has2) {
                    const float4 w2 = *(const float4*)(WATTP + kb * 1280 + l2 * 4);
                    z2 += w2.x * h4.x + w2.y * h4.y + w2.z * h4.z + w2.w * h4.w;
                }
            }
            p_s[r4][l] = z;
            if (has2) p_s[r4][l2] = z2;
        }
        __syncthreads();                                   // B1

        // ---- softmax stats (4 waves per row) ----
        {
            const float za = p_s[rowg][jg];
            const float zb = (jg < 64) ? p_s[rowg][256 + jg] : -3.4e38f;
            float m = fmaxf(za, zb);
            #pragma unroll
            for (int off = 32; off > 0; off >>= 1) m = fmaxf(m, __shfl_xor(m, off));
            if (lane == 0) redM[rowg][wid & 3] = m;
            __syncthreads();                               // B2
            const float M = fmaxf(fmaxf(redM[rowg][0], redM[rowg][1]),
                                  fmaxf(redM[rowg][2], redM[rowg][3]));
            const float ea = __expf(za - M);
            p_s[rowg][jg] = ea;
            float eb = 0.f;
            if (jg < 64) { eb = __expf(zb - M); p_s[rowg][256 + jg] = eb; }
            float sa = ea + eb;
            float sh = (jg >= 44 && jg < 64) ? eb : 0.f;   // l in [300,320)
            #pragma unroll
            for (int off = 32; off > 0; off >>= 1) { sa += __shfl_xor(sa, off); sh += __shfl_xor(sh, off); }
            if (lane == 0) { redS[rowg][wid & 3][0] = sa; redS[rowg][wid & 3][1] = sh; }
        }
        __syncthreads();                                   // B3

        // ---- vocab binning (deterministic index lists) ----
        if (jg < NV) {
            const int o0 = offs16[rowg][jg], o1 = offs16[rowg][jg + 1];
            float s = 0.f;
            for (int o = o0; o < o1; ++o) s += p_s[rowg][idx16[rowg][o]];
            cw_s[rowg][jg] = s;
        }
        __syncthreads();                                   // B4

        // ---- phase 2: x = relu(P2B[xv] + (Q2T.cw + s300*q2pe)/SA) ----
        {
            const int j = q4;
            const float SA  = redS[r4][0][0] + redS[r4][1][0] + redS[r4][2][0] + redS[r4][3][0];
            const float SH  = redS[r4][0][1] + redS[r4][1][1] + redS[r4][2][1] + redS[r4][3][1];
            const float inv = 1.0f / SA;
            const float s300 = SA - SH;
            float acc = s300 * Q2PE[j];
            const float* __restrict__ cwr = cw_s[r4];
            #pragma unroll 5
            for (int vb = 0; vb < 20; ++vb) {
                const float4 qv = *(const float4*)(Q2TP + vb * 1024 + j * 4);
                const float4 cv = *(const float4*)(cwr + vb * 4);
                acc += qv.x * cv.x + qv.y * cv.y + qv.z * cv.z + qv.w * cv.w;
            }
            acc += cwr[80] * Q2TP[20 * 1024 + j * 4];
            const int xv = xd_s[r4];
            x_s[r4][j] = fmaxf(P2B[xv * NH + j] + acc * inv, 0.f);
        }
        __syncthreads();                                   // B5

        // ---- phase 3: gates GEMM (thread = col c, 4 rows) ----
        {
            const int c = tid;
            const float* __restrict__ Wp = WCATPT + c * 4;
            const float* __restrict__ xr = &x_s[0][0];
            const float* __restrict__ hr = &hbuf[pb][0][0];
            float ac0 = 0.f, ac1 = 0.f, ac2 = 0.f, ac3 = 0.f;
            #pragma unroll 4
            for (int kb = 0; kb < 64; ++kb) {
                const float4 w  = *(const float4*)(Wp + kb * 4096);
                const float4 a0 = *(const float4*)(xr + 0 * 260 + kb * 4);
                const float4 a1 = *(const float4*)(xr + 1 * 260 + kb * 4);
                const float4 a2 = *(const float4*)(xr + 2 * 260 + kb * 4);
                const float4 a3 = *(const float4*)(xr + 3 * 260 + kb * 4);
                ac0 += w.x * a0.x + w.y * a0.y + w.z * a0.z + w.w * a0.w;
                ac1 += w.x * a1.x + w.y * a1.y + w.z * a1.z + w.w * a1.w;
                ac2 += w.x * a2.x + w.y * a2.y + w.z * a2.z + w.w * a2.w;
                ac3 += w.x * a3.x + w.y * a3.y + w.z * a3.z + w.w * a3.w;
            }
            #pragma unroll 4
            for (int kb = 0; kb < 64; ++kb) {
                const float4 w  = *(const float4*)(Wp + (64 + kb) * 4096);
                const float4 a0 = *(const float4*)(hr + 0 * 260 + kb * 4);
                const float4 a1 = *(const float4*)(hr + 1 * 260 + kb * 4);
                const float4 a2 = *(const float4*)(hr + 2 * 260 + kb * 4);
                const float4 a3 = *(const float4*)(hr + 3 * 260 + kb * 4);
                ac0 += w.x * a0.x + w.y * a0.y + w.z * a0.z + w.w * a0.w;
                ac1 += w.x * a1.x + w.y * a1.y + w.z * a1.z + w.w * a1.w;
                ac2 += w.x * a2.x + w.y * a2.y + w.z * a2.z + w.w * a2.w;
                ac3 += w.x * a3.x + w.y * a3.y + w.z * a3.z + w.w * a3.w;
            }
            const float bs = bsum_lds[c];
            gex[0][c] = ac0 + bs; gex[1][c] = ac1 + bs;
            gex[2][c] = ac2 + bs; gex[3][c] = ac3 + bs;
        }
        __syncthreads();                                   // B6

        // ---- LSTM pointwise (thread = (rowg, jg), c in register) ----
        {
            const float4 g4 = *(const float4*)(gex[rowg] + 4 * jg);   // i,f,g,o
            creg = sigm(g4.y) * creg + sigm(g4.x) * tanhf_(g4.z);
            hbuf[pb ^ 1][rowg][jg] = sigm(g4.w) * tanhf_(creg);
        }
        __syncthreads();                                   // B7

        // ---- phase 4: fc logits (k-split x2) ----
        if (q4 < 162) {
            const int v  = (q4 < NV) ? q4 : q4 - NV;
            const int ks = (q4 >= NV) ? 1 : 0;
            const float* __restrict__ hr = &hbuf[pb ^ 1][r4][0] + ks * 128;
            const float* __restrict__ wp = WFCTP + ks * 32 * 324 + v * 4;
            float acc = 0.f;
            #pragma unroll 4
            for (int kb = 0; kb < 32; ++kb) {
                const float4 w  = *(const float4*)(wp + kb * 324);
                const float4 h4 = *(const float4*)(hr + kb * 4);
                acc += w.x * h4.x + w.y * h4.y + w.z * h4.z + w.w * h4.w;
            }
            lgpart[ks][r4][v] = acc;
        }
        __syncthreads();                                   // B8
        if (tid < 4 * NV) {
            const int rr = tid / NV, v = tid - rr * NV;
            const float lv = lgpart[0][rr][v] + lgpart[1][rr][v] + bfc_s[v];
            lg_s[rr][v] = lv;
            out_logits[((size_t)t * NB + row0 + rr) * NV + v] = lv;
        }
        __syncthreads();                                   // B9

        // ---- argmax (first-max) + loss, one wave per row ----
        if (wid < 4) {
            const int rr = wid;
            float v0 = lg_s[rr][lane]; int i0 = lane;
            if (lane < NV - 64) {
                const float vb = lg_s[rr][64 + lane];
                if (vb > v0) { v0 = vb; i0 = 64 + lane; }
            }
            #pragma unroll
            for (int off = 32; off > 0; off >>= 1) {
                const float vo = __shfl_xor(v0, off);
                const int   io = __shfl_xor(i0, off);
                if (vo > v0 || (vo == v0 && io < i0)) { v0 = vo; i0 = io; }
            }
            float e = __expf(lg_s[rr][lane] - v0);
            if (lane < NV - 64) e += __expf(lg_s[rr][64 + lane] - v0);
            #pragma unroll
            for (int off = 32; off > 0; off >>= 1) e += __shfl_xor(e, off);
            if (lane == 0) {
                const int y = tgt[(row0 + rr) * NT + t];
                loss_s[rr] += -(lg_s[rr][y] - v0 - logf(e));
                xd_s[rr] = i0;
            }
        }
        __syncthreads();                                   // B10
    }

    if (tid < 4) loss_out[row0 + tid] = loss_s[tid];
}

// ---------------- final mean ----------------
__global__ __launch_bounds__(256) void k_final(const float* __restrict__ loss, float* __restrict__ dst) {
    const int tid = threadIdx.x;
    float v = loss[tid] + loss[tid + 256] + loss[tid + 512] + loss[tid + 768];
    #pragma unroll
    for (int o = 32; o > 0; o >>= 1) v += __shfl_xor(v, o);
    __shared__ float red[4];
    if ((tid & 63) == 0) red[tid >> 6] = v;
    __syncthreads();
    if (tid == 0) dst[0] = (red[0] + red[1] + red[2] + red[3]) / (float)(NB * NT);
}

extern "C" void kernel_launch(void* const* d_in, const int* in_sizes, int n_in,
                              void* d_out, int out_size, void* d_ws, size_t ws_size,
                              hipStream_t stream) {
    const int*   enc    = (const int*)d_in[0];
    const int*   tgt    = (const int*)d_in[1];
    const float* emb    = (const float*)d_in[3];
    const float* W_att  = (const float*)d_in[4];
    const float* b_att  = (const float*)d_in[5];
    const float* W_comb = (const float*)d_in[6];
    const float* b_comb = (const float*)d_in[7];
    const float* W_ih   = (const float*)d_in[8];
    const float* b_ih   = (const float*)d_in[9];
    const float* W_hh   = (const float*)d_in[10];
    const float* b_hh   = (const float*)d_in[11];
    const float* W_fc   = (const float*)d_in[12];
    const float* b_fc   = (const float*)d_in[13];

    float* ws  = (float*)d_ws;
    float* out = (float*)d_out;

    hipLaunchKernelGGL(k_pe,      dim3(1),    dim3(128), 0, stream, ws + OFF_PE);
    hipLaunchKernelGGL(k_tr_att,  dim3(640),  dim3(256), 0, stream, W_att,  ws + OFF_WATT);
    hipLaunchKernelGGL(k_tr_comb, dim3(512),  dim3(256), 0, stream, W_comb, ws + OFF_WCOMBT);
    hipLaunchKernelGGL(k_p1b,     dim3(81),   dim3(320), 0, stream, emb, ws + OFF_WATT, b_att, ws + OFF_P1B);
    hipLaunchKernelGGL(k_p2q,     dim3(81),   dim3(256), 0, stream, emb, ws + OFF_WCOMBT, b_comb,
                       ws + OFF_P2B, ws + OFF_Q2T);
    hipLaunchKernelGGL(k_q2pe,    dim3(1),    dim3(256), 0, stream, ws + OFF_PE, ws + OFF_WCOMBT, ws + OFF_Q2PE);
    hipLaunchKernelGGL(k_pan_cat, dim3(2048), dim3(256), 0, stream, W_ih, W_hh, ws + OFF_WCATPT);
    hipLaunchKernelGGL(k_pan_att, dim3(320),  dim3(256), 0, stream, W_att, ws + OFF_WATTP);
    hipLaunchKernelGGL(k_pan_q2,  dim3(81),   dim3(256), 0, stream, ws + OFF_Q2T, ws + OFF_Q2TP);
    hipLaunchKernelGGL(k_pan_fc,  dim3(81),   dim3(256), 0, stream, W_fc, ws + OFF_WFCTP);

    hipLaunchKernelGGL(k_run, dim3(256), dim3(1024), 0, stream,
                       enc, tgt,
                       ws + OFF_WATTP, ws + OFF_P1B, ws + OFF_P2B,
                       ws + OFF_Q2TP, ws + OFF_Q2PE, ws + OFF_WCATPT, ws + OFF_WFCTP,
                       b_ih, b_hh, b_fc,
                       out, ws + OFF_LOSS);

    hipLaunchKernelGGL(k_final, dim3(1), dim3(256), 0, stream, ws + OFF_LOSS, out + (out_size - 1));
}

// Round 5
// 3995.269 us; speedup vs baseline: 3.3917x; 1.8939x over previous
//
#include <hip/hip_runtime.h>

#define NB 1024
#define SL 300
#define NT 150
#define NH 256
#define LA 320
#define NV 81

typedef _Float16 f16;
typedef _Float16 f16x2 __attribute__((ext_vector_type(2)));

// ws float offsets
#define OFF_WATT    0u         // [512][320] f32 W_att^T (setup intermediate)
#define OFF_WCOMBT  163840u    // [512][256] f32 W_comb^T (intermediate)
#define OFF_P1B     294912u    // [81][320]  f32 emb@W_att[:,:256]^T + b_att
#define OFF_P2B     320832u    // [81][256]  f32 emb@W_comb[:,:256]^T + b_comb
#define OFF_Q2T     341568u    // [81][256]  f32 (intermediate)
#define OFF_Q2PE    362304u    // [256]
#define OFF_PE      362560u    // [256]
#define OFF_Q2TP    362816u    // [21][1024] f32 4v-panel Q2T
#define OFF_WCATPH  384320u    // f16 [64][1024][8] gates weights
#define OFF_WATTPH  646464u    // f16 [32][320][8] h-half W_att^T
#define OFF_WFCPH   687424u    // f16 [32][81][8] W_fc^T
#define OFF_LOSS    697792u    // [1024]

static __device__ __forceinline__ float rcpf(float x)  { return __builtin_amdgcn_rcpf(x); }
static __device__ __forceinline__ float sigm(float x)  { return rcpf(1.f + __expf(-x)); }
static __device__ __forceinline__ float tanhf_(float x){ return 1.f - 2.f * rcpf(1.f + __expf(2.f * x)); }

static __device__ __forceinline__ float dot2(f16x2 a, f16x2 b, float c) {
#if __has_builtin(__builtin_amdgcn_fdot2)
    return __builtin_amdgcn_fdot2(a, b, c, false);
#else
    return c + (float)a[0] * (float)b[0] + (float)a[1] * (float)b[1];
#endif
}
#define DOT4(wf4, af4, acc) { \
    acc = dot2(__builtin_bit_cast(f16x2, (wf4).x), __builtin_bit_cast(f16x2, (af4).x), acc); \
    acc = dot2(__builtin_bit_cast(f16x2, (wf4).y), __builtin_bit_cast(f16x2, (af4).y), acc); \
    acc = dot2(__builtin_bit_cast(f16x2, (wf4).z), __builtin_bit_cast(f16x2, (af4).z), acc); \
    acc = dot2(__builtin_bit_cast(f16x2, (wf4).w), __builtin_bit_cast(f16x2, (af4).w), acc); }

// ---------------- setup kernels ----------------
__global__ __launch_bounds__(128) void k_pe(float* __restrict__ pe) {
    const int i = threadIdx.x;
    const float arg  = (float)(2 * i) * (-0.035977892078031968f);
    const float divf = expf(arg) * 300.0f;
    pe[2 * i]     = (float)sin((double)divf);
    pe[2 * i + 1] = (float)cos((double)divf);
}
__global__ __launch_bounds__(256) void k_tr_att(const float* __restrict__ W, float* __restrict__ WT) {
    const int i = blockIdx.x * 256 + threadIdx.x;
    if (i < 512 * LA) { const int k = i / LA, l = i - k * LA; WT[i] = W[l * 512 + k]; }
}
__global__ __launch_bounds__(256) void k_tr_comb(const float* __restrict__ W, float* __restrict__ WT) {
    const int i = blockIdx.x * 256 + threadIdx.x;
    const int k = i >> 8, j = i & 255;
    if (i < 512 * NH) WT[i] = W[j * 512 + k];
}
__global__ __launch_bounds__(320) void k_p1b(const float* __restrict__ emb, const float* __restrict__ WATT,
                                             const float* __restrict__ b_att, float* __restrict__ P1B) {
    __shared__ float e[NH];
    const int v = blockIdx.x, tid = threadIdx.x;
    if (tid < NH) e[tid] = emb[v * NH + tid];
    __syncthreads();
    float a = b_att[tid];
    #pragma unroll 8
    for (int k = 0; k < NH; ++k) a += e[k] * WATT[k * LA + tid];
    P1B[v * LA + tid] = a;
}
__global__ __launch_bounds__(256) void k_p2q(const float* __restrict__ emb, const float* __restrict__ WCOMBT,
                                             const float* __restrict__ b_comb,
                                             float* __restrict__ P2B, float* __restrict__ Q2T) {
    __shared__ float e[NH];
    const int v = blockIdx.x, tid = threadIdx.x;
    e[tid] = emb[v * NH + tid];
    __syncthreads();
    float a = b_comb[tid], q = 0.f;
    #pragma unroll 8
    for (int k = 0; k < NH; ++k) {
        a += e[k] * WCOMBT[k * NH + tid];
        q += e[k] * WCOMBT[(NH + k) * NH + tid];
    }
    P2B[v * NH + tid] = a;
    Q2T[v * NH + tid] = q;
}
__global__ __launch_bounds__(256) void k_q2pe(const float* __restrict__ pe, const float* __restrict__ WCOMBT,
                                              float* __restrict__ Q2PE) {
    __shared__ float e[NH];
    const int tid = threadIdx.x;
    e[tid] = pe[tid];
    __syncthreads();
    float q = 0.f;
    #pragma unroll 8
    for (int k = 0; k < NH; ++k) q += e[k] * WCOMBT[(NH + k) * NH + tid];
    Q2PE[tid] = q;
}
// Q2T -> 4v panels fp32: elem (v, j) at [(v>>2)*1024 + j*4 + (v&3)]
__global__ __launch_bounds__(256) void k_pan_q2(const float* __restrict__ Q2T, float* __restrict__ P) {
    const int i = blockIdx.x * 256 + threadIdx.x;
    if (i < NV * NH) {
        const int v = i >> 8, j = i & 255;
        P[(v >> 2) * 1024 + j * 4 + (v & 3)] = Q2T[v * NH + j];
    }
}
// gates weights fp16: elem (k, c=j*4+g) at half-index [(k>>3)*8192 + c*8 + (k&7)]
__global__ __launch_bounds__(256) void k_pan_cat_h(const float* __restrict__ Wih, const float* __restrict__ Whh,
                                                   f16* __restrict__ P) {
    const int i = blockIdx.x * 256 + threadIdx.x;
    if (i < 512 * 1024) {
        const int k = i >> 10, c = i & 1023, j = c >> 2, g = c & 3;
        const float v = (k < NH) ? Wih[(g * NH + j) * NH + k] : Whh[(g * NH + j) * NH + (k - NH)];
        P[(k >> 3) * 8192 + c * 8 + (k & 7)] = (f16)v;
    }
}
// h-half W_att^T fp16: elem (k in 0..255, l) at [(k>>3)*2560 + l*8 + (k&7)]
__global__ __launch_bounds__(256) void k_pan_att_h(const float* __restrict__ W, f16* __restrict__ P) {
    const int i = blockIdx.x * 256 + threadIdx.x;
    if (i < 256 * LA) {
        const int k = i / LA, l = i - k * LA;
        P[(k >> 3) * 2560 + l * 8 + (k & 7)] = (f16)W[l * 512 + 256 + k];
    }
}
// W_fc^T fp16: elem (k, v) at [(k>>3)*648 + v*8 + (k&7)]
__global__ __launch_bounds__(256) void k_pan_fc_h(const float* __restrict__ W, f16* __restrict__ P) {
    const int i = blockIdx.x * 256 + threadIdx.x;
    if (i < 256 * NV) {
        const int k = i / NV, v = i - k * NV;
        P[(k >> 3) * 648 + v * 8 + (k & 7)] = (f16)W[v * NH + k];
    }
}

// ---------------- persistent decoder: 256 blocks x 1024 threads, 4 rows/block ----------------
__global__ __launch_bounds__(1024) void k_run(
    const int* __restrict__ enc, const int* __restrict__ tgt,
    const f16* __restrict__ WATTPH, const float* __restrict__ P1B,
    const float* __restrict__ P2B, const float* __restrict__ Q2TP,
    const float* __restrict__ Q2PE, const f16* __restrict__ WCATPH,
    const f16* __restrict__ WFCPH,
    const float* __restrict__ bih, const float* __restrict__ bhh,
    const float* __restrict__ bfc, float* __restrict__ out_logits,
    float* __restrict__ loss_out)
{
    __shared__ __attribute__((aligned(16))) f16 hbufh[2][4][264]; // stride 528B (132w = 4 mod 32)
    __shared__ __attribute__((aligned(16))) f16 xh[4][264];
    __shared__ float p_s[4][324];          // z then exp (pad 324 = 4 mod 32)
    __shared__ float gex[4][1024];         // gate exchange
    __shared__ float bsum_lds[1024];
    __shared__ float cw_s[4][84];
    __shared__ float lg_s[4][84];
    __shared__ float lgpart[2][4][84];
    __shared__ unsigned short idx16[4][SL];
    __shared__ unsigned short cnt16[4][NV];
    __shared__ unsigned short offs16[4][NV + 1];
    __shared__ float redM[4][4];
    __shared__ float redS[4][4][2];
    __shared__ float bfc_s[84];
    __shared__ float loss_s[4];
    __shared__ int   xd_s[4];

    const int tid  = threadIdx.x;
    const int r4   = tid & 3;
    const int q4   = tid >> 2;      // 0..255
    const int rowg = tid >> 8;
    const int jg   = tid & 255;
    const int wid  = tid >> 6;
    const int lane = tid & 63;
    const int row0 = blockIdx.x * 4;

    // ---- init ----
    {
        f16* hz = &hbufh[0][0][0];
        for (int i = tid; i < 2 * 4 * 264; i += 1024) hz[i] = (f16)0.f;
        f16* xz = &xh[0][0];
        for (int i = tid; i < 4 * 264; i += 1024) xz[i] = (f16)0.f;
    }
    { const int j = tid >> 2, g = tid & 3; bsum_lds[tid] = bih[g * NH + j] + bhh[g * NH + j]; }
    if (tid < 84) bfc_s[tid] = (tid < NV) ? bfc[tid] : 0.f;
    if (tid < 4) { xd_s[tid] = 1; loss_s[tid] = 0.f; }
    const int* __restrict__ encr = enc + (row0 + rowg) * SL;
    if (jg < NV) {
        int c = 0;
        for (int l = 0; l < SL; ++l) c += (encr[l] == jg);
        cnt16[rowg][jg] = (unsigned short)c;
    }
    __syncthreads();
    if (jg == 0) {
        int o = 0; offs16[rowg][0] = 0;
        for (int v = 0; v < NV; ++v) { o += cnt16[rowg][v]; offs16[rowg][v + 1] = (unsigned short)o; }
    }
    __syncthreads();
    if (jg < NV) {
        int o = offs16[rowg][jg];
        for (int l = 0; l < SL; ++l) if (encr[l] == jg) idx16[rowg][o++] = (unsigned short)l;
    }
    __syncthreads();

    float creg = 0.f;   // cell state for (rowg, jg)

    for (int t = 0; t < NT; ++t) {
        const int pb = t & 1;

        // ---- phase 1: attention logits z (fp16 dot2) ----
        {
            const int l = q4;
            const int xv = xd_s[r4];
            const f16* __restrict__ hr = &hbufh[pb][r4][0];
            float z = P1B[xv * LA + l];
            const bool has2 = (tid < 256);
            const int l2 = 256 + q4;
            float z2 = has2 ? P1B[xv * LA + l2] : 0.f;
            #pragma unroll 4
            for (int kb = 0; kb < 32; ++kb) {
                const float4 h4 = *(const float4*)(hr + kb * 8);
                const float4 w  = *(const float4*)(WATTPH + kb * 2560 + l * 8);
                DOT4(w, h4, z);
                if (has2) {
                    const float4 w2 = *(const float4*)(WATTPH + kb * 2560 + l2 * 8);
                    DOT4(w2, h4, z2);
                }
            }
            p_s[r4][l] = z;
            if (has2) p_s[r4][l2] = z2;
        }
        __syncthreads();                                   // B1

        // ---- softmax stats ----
        {
            const float za = p_s[rowg][jg];
            const float zb = (jg < 64) ? p_s[rowg][256 + jg] : -3.4e38f;
            float m = fmaxf(za, zb);
            #pragma unroll
            for (int off = 32; off > 0; off >>= 1) m = fmaxf(m, __shfl_xor(m, off));
            if (lane == 0) redM[rowg][wid & 3] = m;
            __syncthreads();                               // B2
            const float M = fmaxf(fmaxf(redM[rowg][0], redM[rowg][1]),
                                  fmaxf(redM[rowg][2], redM[rowg][3]));
            const float ea = __expf(za - M);
            p_s[rowg][jg] = ea;
            float eb = 0.f;
            if (jg < 64) { eb = __expf(zb - M); p_s[rowg][256 + jg] = eb; }
            float sa = ea + eb;
            float sh = (jg >= 44 && jg < 64) ? eb : 0.f;   // l in [300,320)
            #pragma unroll
            for (int off = 32; off > 0; off >>= 1) { sa += __shfl_xor(sa, off); sh += __shfl_xor(sh, off); }
            if (lane == 0) { redS[rowg][wid & 3][0] = sa; redS[rowg][wid & 3][1] = sh; }
        }
        __syncthreads();                                   // B3

        // ---- vocab binning ----
        if (jg < NV) {
            const int o0 = offs16[rowg][jg], o1 = offs16[rowg][jg + 1];
            float s = 0.f;
            for (int o = o0; o < o1; ++o) s += p_s[rowg][idx16[rowg][o]];
            cw_s[rowg][jg] = s;
        }
        __syncthreads();                                   // B4

        // ---- phase 2: x = relu(P2B[xv] + (Q2T.cw + s300*q2pe)/SA), store fp16 ----
        {
            const int j = q4;
            const float SA  = redS[r4][0][0] + redS[r4][1][0] + redS[r4][2][0] + redS[r4][3][0];
            const float SH  = redS[r4][0][1] + redS[r4][1][1] + redS[r4][2][1] + redS[r4][3][1];
            const float inv = 1.0f / SA;
            const float s300 = SA - SH;
            float acc = s300 * Q2PE[j];
            const float* __restrict__ cwr = cw_s[r4];
            #pragma unroll 5
            for (int vb = 0; vb < 20; ++vb) {
                const float4 qv = *(const float4*)(Q2TP + vb * 1024 + j * 4);
                const float4 cv = *(const float4*)(cwr + vb * 4);
                acc += qv.x * cv.x + qv.y * cv.y + qv.z * cv.z + qv.w * cv.w;
            }
            acc += cwr[80] * Q2TP[20 * 1024 + j * 4];
            const int xv = xd_s[r4];
            xh[r4][j] = (f16)fmaxf(P2B[xv * NH + j] + acc * inv, 0.f);
        }
        __syncthreads();                                   // B5

        // ---- phase 3: gates GEMM fp16 dot2 (thread = col c, 4 rows) ----
        {
            const int c = tid;
            const f16* __restrict__ Wp = WCATPH + (size_t)c * 8;
            float ac0 = 0.f, ac1 = 0.f, ac2 = 0.f, ac3 = 0.f;
            #pragma unroll 4
            for (int kb = 0; kb < 32; ++kb) {
                const float4 w  = *(const float4*)(Wp + kb * 8192);
                const float4 a0 = *(const float4*)(&xh[0][kb * 8]);
                const float4 a1 = *(const float4*)(&xh[1][kb * 8]);
                const float4 a2 = *(const float4*)(&xh[2][kb * 8]);
                const float4 a3 = *(const float4*)(&xh[3][kb * 8]);
                DOT4(w, a0, ac0); DOT4(w, a1, ac1);
                DOT4(w, a2, ac2); DOT4(w, a3, ac3);
            }
            #pragma unroll 4
            for (int kb = 0; kb < 32; ++kb) {
                const float4 w  = *(const float4*)(Wp + (32 + kb) * 8192);
                const float4 a0 = *(const float4*)(&hbufh[pb][0][kb * 8]);
                const float4 a1 = *(const float4*)(&hbufh[pb][1][kb * 8]);
                const float4 a2 = *(const float4*)(&hbufh[pb][2][kb * 8]);
                const float4 a3 = *(const float4*)(&hbufh[pb][3][kb * 8]);
                DOT4(w, a0, ac0); DOT4(w, a1, ac1);
                DOT4(w, a2, ac2); DOT4(w, a3, ac3);
            }
            const float bs = bsum_lds[c];
            gex[0][c] = ac0 + bs; gex[1][c] = ac1 + bs;
            gex[2][c] = ac2 + bs; gex[3][c] = ac3 + bs;
        }
        __syncthreads();                                   // B6

        // ---- LSTM pointwise ----
        {
            const float4 g4 = *(const float4*)(gex[rowg] + 4 * jg);   // i,f,g,o
            creg = sigm(g4.y) * creg + sigm(g4.x) * tanhf_(g4.z);
            hbufh[pb ^ 1][rowg][jg] = (f16)(sigm(g4.w) * tanhf_(creg));
        }
        __syncthreads();                                   // B7

        // ---- phase 4: fc logits fp16 dot2 (k-split x2) ----
        if (q4 < 2 * NV) {
            const int v  = (q4 < NV) ? q4 : q4 - NV;
            const int ks = (q4 >= NV) ? 1 : 0;
            const f16* __restrict__ hr = &hbufh[pb ^ 1][r4][ks * 128];
            const f16* __restrict__ wp = WFCPH + (ks * 16) * 648 + v * 8;
            float acc = 0.f;
            #pragma unroll 4
            for (int kb = 0; kb < 16; ++kb) {
                const float4 w  = *(const float4*)(wp + kb * 648);
                const float4 h4 = *(const float4*)(hr + kb * 8);
                DOT4(w, h4, acc);
            }
            lgpart[ks][r4][v] = acc;
        }
        __syncthreads();                                   // B8
        if (tid < 4 * NV) {
            const int rr = tid / NV, v = tid - rr * NV;
            const float lv = lgpart[0][rr][v] + lgpart[1][rr][v] + bfc_s[v];
            lg_s[rr][v] = lv;
            out_logits[((size_t)t * NB + row0 + rr) * NV + v] = lv;
        }
        __syncthreads();                                   // B9

        // ---- argmax (first-max) + loss ----
        if (wid < 4) {
            const int rr = wid;
            float v0 = lg_s[rr][lane]; int i0 = lane;
            if (lane < NV - 64) {
                const float vb = lg_s[rr][64 + lane];
                if (vb > v0) { v0 = vb; i0 = 64 + lane; }
            }
            #pragma unroll
            for (int off = 32; off > 0; off >>= 1) {
                const float vo = __shfl_xor(v0, off);
                const int   io = __shfl_xor(i0, off);
                if (vo > v0 || (vo == v0 && io < i0)) { v0 = vo; i0 = io; }
            }
            float e = __expf(lg_s[rr][lane] - v0);
            if (lane < NV - 64) e += __expf(lg_s[rr][64 + lane] - v0);
            #pragma unroll
            for (int off = 32; off > 0; off >>= 1) e += __shfl_xor(e, off);
            if (lane == 0) {
                const int y = tgt[(row0 + rr) * NT + t];
                loss_s[rr] += -(lg_s[rr][y] - v0 - logf(e));
                xd_s[rr] = i0;
            }
        }
        __syncthreads();                                   // B10
    }

    if (tid < 4) loss_out[row0 + tid] = loss_s[tid];
}

// ---------------- final mean ----------------
__global__ __launch_bounds__(256) void k_final(const float* __restrict__ loss, float* __restrict__ dst) {
    const int tid = threadIdx.x;
    float v = loss[tid] + loss[tid + 256] + loss[tid + 512] + loss[tid + 768];
    #pragma unroll
    for (int o = 32; o > 0; o >>= 1) v += __shfl_xor(v, o);
    __shared__ float red[4];
    if ((tid & 63) == 0) red[tid >> 6] = v;
    __syncthreads();
    if (tid == 0) dst[0] = (red[0] + red[1] + red[2] + red[3]) / (float)(NB * NT);
}

extern "C" void kernel_launch(void* const* d_in, const int* in_sizes, int n_in,
                              void* d_out, int out_size, void* d_ws, size_t ws_size,
                              hipStream_t stream) {
    const int*   enc    = (const int*)d_in[0];
    const int*   tgt    = (const int*)d_in[1];
    const float* emb    = (const float*)d_in[3];
    const float* W_att  = (const float*)d_in[4];
    const float* b_att  = (const float*)d_in[5];
    const float* W_comb = (const float*)d_in[6];
    const float* b_comb = (const float*)d_in[7];
    const float* W_ih   = (const float*)d_in[8];
    const float* b_ih   = (const float*)d_in[9];
    const float* W_hh   = (const float*)d_in[10];
    const float* b_hh   = (const float*)d_in[11];
    const float* W_fc   = (const float*)d_in[12];
    const float* b_fc   = (const float*)d_in[13];

    float* ws  = (float*)d_ws;
    float* out = (float*)d_out;
    f16* WCATPH = (f16*)(ws + OFF_WCATPH);
    f16* WATTPH = (f16*)(ws + OFF_WATTPH);
    f16* WFCPH  = (f16*)(ws + OFF_WFCPH);

    hipLaunchKernelGGL(k_pe,      dim3(1),    dim3(128), 0, stream, ws + OFF_PE);
    hipLaunchKernelGGL(k_tr_att,  dim3(640),  dim3(256), 0, stream, W_att,  ws + OFF_WATT);
    hipLaunchKernelGGL(k_tr_comb, dim3(512),  dim3(256), 0, stream, W_comb, ws + OFF_WCOMBT);
    hipLaunchKernelGGL(k_p1b,     dim3(81),   dim3(320), 0, stream, emb, ws + OFF_WATT, b_att, ws + OFF_P1B);
    hipLaunchKernelGGL(k_p2q,     dim3(81),   dim3(256), 0, stream, emb, ws + OFF_WCOMBT, b_comb,
                       ws + OFF_P2B, ws + OFF_Q2T);
    hipLaunchKernelGGL(k_q2pe,    dim3(1),    dim3(256), 0, stream, ws + OFF_PE, ws + OFF_WCOMBT, ws + OFF_Q2PE);
    hipLaunchKernelGGL(k_pan_q2,  dim3(81),   dim3(256), 0, stream, ws + OFF_Q2T, ws + OFF_Q2TP);
    hipLaunchKernelGGL(k_pan_cat_h, dim3(2048), dim3(256), 0, stream, W_ih, W_hh, WCATPH);
    hipLaunchKernelGGL(k_pan_att_h, dim3(320),  dim3(256), 0, stream, W_att, WATTPH);
    hipLaunchKernelGGL(k_pan_fc_h,  dim3(81),   dim3(256), 0, stream, W_fc, WFCPH);

    hipLaunchKernelGGL(k_run, dim3(256), dim3(1024), 0, stream,
                       enc, tgt,
                       WATTPH, ws + OFF_P1B, ws + OFF_P2B,
                       ws + OFF_Q2TP, ws + OFF_Q2PE, WCATPH, WFCPH,
                       b_ih, b_hh, b_fc,
                       out, ws + OFF_LOSS);

    hipLaunchKernelGGL(k_final, dim3(1), dim3(256), 0, stream, ws + OFF_LOSS, out + (out_size - 1));
}

// Round 6
// 2651.744 us; speedup vs baseline: 5.1102x; 1.5067x over previous
//
#include <hip/hip_runtime.h>

#define NB 1024
#define SL 300
#define NT 150
#define NH 256
#define LA 320
#define NV 81

typedef _Float16 f16;
typedef _Float16 f16x2 __attribute__((ext_vector_type(2)));
typedef _Float16 f16x8 __attribute__((ext_vector_type(8)));
typedef float    f32x4 __attribute__((ext_vector_type(4)));

// ws float offsets
#define OFF_WATT    0u         // [512][320] f32 W_att^T (setup intermediate)
#define OFF_WCOMBT  163840u    // [512][256] f32 W_comb^T (intermediate)
#define OFF_P1B     294912u    // [81][320]  f32 emb@W_att[:,:256]^T + b_att
#define OFF_P2B     320832u    // [81][256]  f32 emb@W_comb[:,:256]^T + b_comb
#define OFF_Q2T     341568u    // [81][256]  f32 (intermediate)
#define OFF_Q2PE    362304u    // [256]
#define OFF_PE      362560u    // [256]
#define OFF_Q2TP    362816u    // [21][1024] f32 4v-panel Q2T
#define OFF_WCATM   384320u    // f16 MFMA-frag gates weights [64 nt][16 kw][64 lane][8]
#define OFF_WATTM   646464u    // f16 MFMA-frag attn-h weights [20 nt][8 kw][64 lane][8]
#define OFF_WFCPH   687424u    // f16 [32][81][8] W_fc^T (dot2 layout)
#define OFF_LOSS    697792u    // [1024]

static __device__ __forceinline__ float rcpf(float x)  { return __builtin_amdgcn_rcpf(x); }
static __device__ __forceinline__ float sigm(float x)  { return rcpf(1.f + __expf(-x)); }
static __device__ __forceinline__ float tanhf_(float x){ return 1.f - 2.f * rcpf(1.f + __expf(2.f * x)); }

static __device__ __forceinline__ float dot2(f16x2 a, f16x2 b, float c) {
#if __has_builtin(__builtin_amdgcn_fdot2)
    return __builtin_amdgcn_fdot2(a, b, c, false);
#else
    return c + (float)a[0] * (float)b[0] + (float)a[1] * (float)b[1];
#endif
}
#define DOT4(wf4, af4, acc) { \
    acc = dot2(__builtin_bit_cast(f16x2, (wf4).x), __builtin_bit_cast(f16x2, (af4).x), acc); \
    acc = dot2(__builtin_bit_cast(f16x2, (wf4).y), __builtin_bit_cast(f16x2, (af4).y), acc); \
    acc = dot2(__builtin_bit_cast(f16x2, (wf4).z), __builtin_bit_cast(f16x2, (af4).z), acc); \
    acc = dot2(__builtin_bit_cast(f16x2, (wf4).w), __builtin_bit_cast(f16x2, (af4).w), acc); }

// ---------------- setup kernels ----------------
__global__ __launch_bounds__(128) void k_pe(float* __restrict__ pe) {
    const int i = threadIdx.x;
    const float arg  = (float)(2 * i) * (-0.035977892078031968f);
    const float divf = expf(arg) * 300.0f;
    pe[2 * i]     = (float)sin((double)divf);
    pe[2 * i + 1] = (float)cos((double)divf);
}
__global__ __launch_bounds__(256) void k_tr_att(const float* __restrict__ W, float* __restrict__ WT) {
    const int i = blockIdx.x * 256 + threadIdx.x;
    if (i < 512 * LA) { const int k = i / LA, l = i - k * LA; WT[i] = W[l * 512 + k]; }
}
__global__ __launch_bounds__(256) void k_tr_comb(const float* __restrict__ W, float* __restrict__ WT) {
    const int i = blockIdx.x * 256 + threadIdx.x;
    const int k = i >> 8, j = i & 255;
    if (i < 512 * NH) WT[i] = W[j * 512 + k];
}
__global__ __launch_bounds__(320) void k_p1b(const float* __restrict__ emb, const float* __restrict__ WATT,
                                             const float* __restrict__ b_att, float* __restrict__ P1B) {
    __shared__ float e[NH];
    const int v = blockIdx.x, tid = threadIdx.x;
    if (tid < NH) e[tid] = emb[v * NH + tid];
    __syncthreads();
    float a = b_att[tid];
    #pragma unroll 8
    for (int k = 0; k < NH; ++k) a += e[k] * WATT[k * LA + tid];
    P1B[v * LA + tid] = a;
}
__global__ __launch_bounds__(256) void k_p2q(const float* __restrict__ emb, const float* __restrict__ WCOMBT,
                                             const float* __restrict__ b_comb,
                                             float* __restrict__ P2B, float* __restrict__ Q2T) {
    __shared__ float e[NH];
    const int v = blockIdx.x, tid = threadIdx.x;
    e[tid] = emb[v * NH + tid];
    __syncthreads();
    float a = b_comb[tid], q = 0.f;
    #pragma unroll 8
    for (int k = 0; k < NH; ++k) {
        a += e[k] * WCOMBT[k * NH + tid];
        q += e[k] * WCOMBT[(NH + k) * NH + tid];
    }
    P2B[v * NH + tid] = a;
    Q2T[v * NH + tid] = q;
}
__global__ __launch_bounds__(256) void k_q2pe(const float* __restrict__ pe, const float* __restrict__ WCOMBT,
                                              float* __restrict__ Q2PE) {
    __shared__ float e[NH];
    const int tid = threadIdx.x;
    e[tid] = pe[tid];
    __syncthreads();
    float q = 0.f;
    #pragma unroll 8
    for (int k = 0; k < NH; ++k) q += e[k] * WCOMBT[(NH + k) * NH + tid];
    Q2PE[tid] = q;
}
// Q2T -> 4v panels fp32
__global__ __launch_bounds__(256) void k_pan_q2(const float* __restrict__ Q2T, float* __restrict__ P) {
    const int i = blockIdx.x * 256 + threadIdx.x;
    if (i < NV * NH) {
        const int v = i >> 8, j = i & 255;
        P[(v >> 2) * 1024 + j * 4 + (v & 3)] = Q2T[v * NH + j];
    }
}
// gates weights -> MFMA B-frag order. B[k][c], k in [0,512), c = j*4+g in [0,1024)
// frag: lane l holds B[k = kw*32 + (l>>4)*8 + jj][col = nt*16 + (l&15)]
// dst halves: nt*8192 + kw*512 + l*8 + jj
__global__ __launch_bounds__(256) void k_pan_cat_m(const float* __restrict__ Wih, const float* __restrict__ Whh,
                                                   f16* __restrict__ P) {
    const int i = blockIdx.x * 256 + threadIdx.x;
    if (i < 512 * 1024) {
        const int k = i >> 10, c = i & 1023, jcol = c >> 2, g = c & 3;
        const float v = (k < NH) ? Wih[(g * NH + jcol) * NH + k] : Whh[(g * NH + jcol) * NH + (k - NH)];
        const int nt = c >> 4, kw = k >> 5, kr = k & 31;
        const int l = (kr >> 3) * 16 + (c & 15), jj = kr & 7;
        P[nt * 8192 + kw * 512 + l * 8 + jj] = (f16)v;
    }
}
// attn-h weights -> MFMA B-frag order. B[k][lcol] = W_att[lcol][256+k], k in [0,256), lcol in [0,320)
// dst halves: nt*4096 + kw*512 + l*8 + jj
__global__ __launch_bounds__(256) void k_pan_att_m(const float* __restrict__ W, f16* __restrict__ P) {
    const int i = blockIdx.x * 256 + threadIdx.x;
    if (i < 256 * LA) {
        const int k = i / LA, lcol = i - k * LA;
        const float v = W[lcol * 512 + 256 + k];
        const int nt = lcol >> 4, kw = k >> 5, kr = k & 31;
        const int l = (kr >> 3) * 16 + (lcol & 15), jj = kr & 7;
        P[nt * 4096 + kw * 512 + l * 8 + jj] = (f16)v;
    }
}
// W_fc^T fp16 dot2 layout: elem (k, v) at [(k>>3)*648 + v*8 + (k&7)]
__global__ __launch_bounds__(256) void k_pan_fc_h(const float* __restrict__ W, f16* __restrict__ P) {
    const int i = blockIdx.x * 256 + threadIdx.x;
    if (i < 256 * NV) {
        const int k = i / NV, v = i - k * NV;
        P[(k >> 3) * 648 + v * 8 + (k & 7)] = (f16)W[v * NH + k];
    }
}

// ---------------- persistent decoder: 256 blocks x 1024 threads, 4 rows/block ----------------
__global__ __launch_bounds__(1024, 4) void k_run(
    const int* __restrict__ enc, const int* __restrict__ tgt,
    const f16* __restrict__ WATTM, const float* __restrict__ P1B,
    const float* __restrict__ P2B, const float* __restrict__ Q2TP,
    const float* __restrict__ Q2PE, const f16* __restrict__ WCATM,
    const f16* __restrict__ WFCPH,
    const float* __restrict__ bih, const float* __restrict__ bhh,
    const float* __restrict__ bfc, float* __restrict__ out_logits,
    float* __restrict__ loss_out)
{
    __shared__ __attribute__((aligned(16))) f16 hbufh[2][4][264]; // 528B row stride
    __shared__ __attribute__((aligned(16))) f16 xh[4][264];
    __shared__ float p_s[4][324];          // raw z then exp
    __shared__ float gex[4][1024];         // gate exchange (no bias)
    __shared__ float bsum_lds[1024];
    __shared__ float cw_s[4][84];
    __shared__ float lg_s[4][84];
    __shared__ float lgpart[2][4][84];
    __shared__ unsigned short idx16[4][SL];
    __shared__ unsigned short cnt16[4][NV];
    __shared__ unsigned short offs16[4][NV + 1];
    __shared__ float redM[4][4];
    __shared__ float redS[4][4][2];
    __shared__ float bfc_s[84];
    __shared__ float loss_s[4];
    __shared__ int   xd_s[4];

    const int tid  = threadIdx.x;
    const int r4   = tid & 3;
    const int q4   = tid >> 2;      // 0..255
    const int rowg = tid >> 8;
    const int jg   = tid & 255;
    const int wid  = tid >> 6;
    const int lane = tid & 63;
    const int row0 = blockIdx.x * 4;
    // MFMA lane decomposition
    const int arow = lane & 3;      // (lane&15)&3 == lane&3 only for lane&15<16; use (lane&15)&3
    const int mrow = lane & 15;
    const int arow4 = mrow & 3;     // A-row folded
    const int khi  = lane >> 4;

    // ---- init ----
    {
        f16* hz = &hbufh[0][0][0];
        for (int i = tid; i < 2 * 4 * 264; i += 1024) hz[i] = (f16)0.f;
        f16* xz = &xh[0][0];
        for (int i = tid; i < 4 * 264; i += 1024) xz[i] = (f16)0.f;
    }
    { const int j = tid >> 2, g = tid & 3; bsum_lds[tid] = bih[g * NH + j] + bhh[g * NH + j]; }
    if (tid < 84) bfc_s[tid] = (tid < NV) ? bfc[tid] : 0.f;
    if (tid < 4 * 84) { cw_s[tid / 84][tid % 84] = 0.f; }
    if (tid < 4) { xd_s[tid] = 1; loss_s[tid] = 0.f; }
    const int* __restrict__ encr = enc + (row0 + rowg) * SL;
    if (jg < NV) {
        int c = 0;
        for (int l = 0; l < SL; ++l) c += (encr[l] == jg);
        cnt16[rowg][jg] = (unsigned short)c;
    }
    __syncthreads();
    if (jg == 0) {
        int o = 0; offs16[rowg][0] = 0;
        for (int v = 0; v < NV; ++v) { o += cnt16[rowg][v]; offs16[rowg][v + 1] = (unsigned short)o; }
    }
    __syncthreads();
    if (jg < NV) {
        int o = offs16[rowg][jg];
        for (int l = 0; l < SL; ++l) if (encr[l] == jg) idx16[rowg][o++] = (unsigned short)l;
    }
    __syncthreads();

    float creg = 0.f;   // cell state for (rowg, jg)
    (void)arow;

    for (int t = 0; t < NT; ++t) {
        const int pb = t & 1;

        // ---- phase 1: attention z via MFMA (wave=ntile; waves 0-3 take a 2nd ntile) ----
        {
            f32x4 za0 = {0.f, 0.f, 0.f, 0.f}, za1 = {0.f, 0.f, 0.f, 0.f};
            const bool two = (wid < 4);
            const f16* __restrict__ B0 = WATTM + wid * 4096 + lane * 8;
            const f16* __restrict__ B1 = WATTM + (16 + wid) * 4096 + lane * 8;
            const f16* __restrict__ hr = &hbufh[pb][arow4][khi * 8];
            #pragma unroll 4
            for (int kw = 0; kw < 8; ++kw) {
                const f16x8 a = *(const f16x8*)(hr + kw * 32);
                const f16x8 b0 = *(const f16x8*)(B0 + kw * 512);
                za0 = __builtin_amdgcn_mfma_f32_16x16x32_f16(a, b0, za0, 0, 0, 0);
                if (two) {
                    const f16x8 b1 = *(const f16x8*)(B1 + kw * 512);
                    za1 = __builtin_amdgcn_mfma_f32_16x16x32_f16(a, b1, za1, 0, 0, 0);
                }
            }
            if (lane < 16) {
                #pragma unroll
                for (int i = 0; i < 4; ++i) p_s[i][wid * 16 + mrow] = za0[i];
                if (two) {
                    #pragma unroll
                    for (int i = 0; i < 4; ++i) p_s[i][256 + wid * 16 + mrow] = za1[i];
                }
            }
        }
        __syncthreads();                                   // B1

        // ---- softmax stats (adds P1B here) ----
        {
            const float* __restrict__ P1r = P1B + xd_s[rowg] * LA;
            const float za = p_s[rowg][jg] + P1r[jg];
            const float zb = (jg < 64) ? (p_s[rowg][256 + jg] + P1r[256 + jg]) : -3.4e38f;
            float m = fmaxf(za, zb);
            #pragma unroll
            for (int off = 32; off > 0; off >>= 1) m = fmaxf(m, __shfl_xor(m, off));
            if (lane == 0) redM[rowg][wid & 3] = m;
            __syncthreads();                               // B2
            const float M = fmaxf(fmaxf(redM[rowg][0], redM[rowg][1]),
                                  fmaxf(redM[rowg][2], redM[rowg][3]));
            const float ea = __expf(za - M);
            p_s[rowg][jg] = ea;
            float eb = 0.f;
            if (jg < 64) { eb = __expf(zb - M); p_s[rowg][256 + jg] = eb; }
            float sa = ea + eb;
            float sh = (jg >= 44 && jg < 64) ? eb : 0.f;   // l in [300,320)
            #pragma unroll
            for (int off = 32; off > 0; off >>= 1) { sa += __shfl_xor(sa, off); sh += __shfl_xor(sh, off); }
            if (lane == 0) { redS[rowg][wid & 3][0] = sa; redS[rowg][wid & 3][1] = sh; }
        }
        __syncthreads();                                   // B3

        // ---- vocab binning ----
        if (jg < NV) {
            const int o0 = offs16[rowg][jg], o1 = offs16[rowg][jg + 1];
            float s = 0.f;
            for (int o = o0; o < o1; ++o) s += p_s[rowg][idx16[rowg][o]];
            cw_s[rowg][jg] = s;
        }
        __syncthreads();                                   // B4

        // ---- phase 2: x = relu(P2B[xv] + (Q2T.cw + s300*q2pe)/SA), store fp16 ----
        {
            const int j = q4;
            const float SA  = redS[r4][0][0] + redS[r4][1][0] + redS[r4][2][0] + redS[r4][3][0];
            const float SH  = redS[r4][0][1] + redS[r4][1][1] + redS[r4][2][1] + redS[r4][3][1];
            const float inv = 1.0f / SA;
            const float s300 = SA - SH;
            float acc = s300 * Q2PE[j];
            const float* __restrict__ cwr = cw_s[r4];
            #pragma unroll 5
            for (int vb = 0; vb < 20; ++vb) {
                const float4 qv = *(const float4*)(Q2TP + vb * 1024 + j * 4);
                const float4 cv = *(const float4*)(cwr + vb * 4);
                acc += qv.x * cv.x + qv.y * cv.y + qv.z * cv.z + qv.w * cv.w;
            }
            acc += cwr[80] * Q2TP[20 * 1024 + j * 4];
            const int xv = xd_s[r4];
            xh[r4][j] = (f16)fmaxf(P2B[xv * NH + j] + acc * inv, 0.f);
        }
        __syncthreads();                                   // B5

        // ---- phase 3: gates GEMM via MFMA (wave = 4 ntiles of 16 cols; 16 kw) ----
        {
            f32x4 acc0 = {0.f,0.f,0.f,0.f}, acc1 = {0.f,0.f,0.f,0.f};
            f32x4 acc2 = {0.f,0.f,0.f,0.f}, acc3 = {0.f,0.f,0.f,0.f};
            const f16* __restrict__ BG = WCATM + (size_t)wid * 4 * 8192 + lane * 8;
            const f16* __restrict__ xr = &xh[arow4][khi * 8];
            const f16* __restrict__ hr = &hbufh[pb][arow4][khi * 8];
            #pragma unroll 4
            for (int kw = 0; kw < 16; ++kw) {
                const f16x8 a = (kw < 8) ? *(const f16x8*)(xr + kw * 32)
                                         : *(const f16x8*)(hr + (kw - 8) * 32);
                const f16* bp = BG + kw * 512;
                const f16x8 b0 = *(const f16x8*)(bp);
                const f16x8 b1 = *(const f16x8*)(bp + 8192);
                const f16x8 b2 = *(const f16x8*)(bp + 16384);
                const f16x8 b3 = *(const f16x8*)(bp + 24576);
                acc0 = __builtin_amdgcn_mfma_f32_16x16x32_f16(a, b0, acc0, 0, 0, 0);
                acc1 = __builtin_amdgcn_mfma_f32_16x16x32_f16(a, b1, acc1, 0, 0, 0);
                acc2 = __builtin_amdgcn_mfma_f32_16x16x32_f16(a, b2, acc2, 0, 0, 0);
                acc3 = __builtin_amdgcn_mfma_f32_16x16x32_f16(a, b3, acc3, 0, 0, 0);
            }
            if (lane < 16) {
                const int c0 = wid * 64 + mrow;
                #pragma unroll
                for (int i = 0; i < 4; ++i) {
                    gex[i][c0]      = acc0[i];
                    gex[i][c0 + 16] = acc1[i];
                    gex[i][c0 + 32] = acc2[i];
                    gex[i][c0 + 48] = acc3[i];
                }
            }
        }
        __syncthreads();                                   // B6

        // ---- LSTM pointwise (adds bias here) ----
        {
            const float4 g4 = *(const float4*)(gex[rowg] + 4 * jg);   // i,f,g,o
            const float4 b4 = *(const float4*)(bsum_lds + 4 * jg);
            creg = sigm(g4.y + b4.y) * creg + sigm(g4.x + b4.x) * tanhf_(g4.z + b4.z);
            hbufh[pb ^ 1][rowg][jg] = (f16)(sigm(g4.w + b4.w) * tanhf_(creg));
        }
        __syncthreads();                                   // B7

        // ---- phase 4: fc logits fp16 dot2 (k-split x2) ----
        if (q4 < 2 * NV) {
            const int v  = (q4 < NV) ? q4 : q4 - NV;
            const int ks = (q4 >= NV) ? 1 : 0;
            const f16* __restrict__ hr = &hbufh[pb ^ 1][r4][ks * 128];
            const f16* __restrict__ wp = WFCPH + (ks * 16) * 648 + v * 8;
            float acc = 0.f;
            #pragma unroll 4
            for (int kb = 0; kb < 16; ++kb) {
                const float4 w  = *(const float4*)(wp + kb * 648);
                const float4 h4 = *(const float4*)(hr + kb * 8);
                DOT4(w, h4, acc);
            }
            lgpart[ks][r4][v] = acc;
        }
        __syncthreads();                                   // B8
        if (tid < 4 * NV) {
            const int rr = tid / NV, v = tid - rr * NV;
            const float lv = lgpart[0][rr][v] + lgpart[1][rr][v] + bfc_s[v];
            lg_s[rr][v] = lv;
            out_logits[((size_t)t * NB + row0 + rr) * NV + v] = lv;
        }
        __syncthreads();                                   // B9

        // ---- argmax (first-max) + loss ----
        if (wid < 4) {
            const int rr = wid;
            float v0 = lg_s[rr][lane]; int i0 = lane;
            if (lane < NV - 64) {
                const float vb = lg_s[rr][64 + lane];
                if (vb > v0) { v0 = vb; i0 = 64 + lane; }
            }
            #pragma unroll
            for (int off = 32; off > 0; off >>= 1) {
                const float vo = __shfl_xor(v0, off);
                const int   io = __shfl_xor(i0, off);
                if (vo > v0 || (vo == v0 && io < i0)) { v0 = vo; i0 = io; }
            }
            float e = __expf(lg_s[rr][lane] - v0);
            if (lane < NV - 64) e += __expf(lg_s[rr][64 + lane] - v0);
            #pragma unroll
            for (int off = 32; off > 0; off >>= 1) e += __shfl_xor(e, off);
            if (lane == 0) {
                const int y = tgt[(row0 + rr) * NT + t];
                loss_s[rr] += -(lg_s[rr][y] - v0 - logf(e));
                xd_s[rr] = i0;
            }
        }
        __syncthreads();                                   // B10
    }

    if (tid < 4) loss_out[row0 + tid] = loss_s[tid];
}

// ---------------- final mean ----------------
__global__ __launch_bounds__(256) void k_final(const float* __restrict__ loss, float* __restrict__ dst) {
    const int tid = threadIdx.x;
    float v = loss[tid] + loss[tid + 256] + loss[tid + 512] + loss[tid + 768];
    #pragma unroll
    for (int o = 32; o > 0; o >>= 1) v += __shfl_xor(v, o);
    __shared__ float red[4];
    if ((tid & 63) == 0) red[tid >> 6] = v;
    __syncthreads();
    if (tid == 0) dst[0] = (red[0] + red[1] + red[2] + red[3]) / (float)(NB * NT);
}

extern "C" void kernel_launch(void* const* d_in, const int* in_sizes, int n_in,
                              void* d_out, int out_size, void* d_ws, size_t ws_size,
                              hipStream_t stream) {
    const int*   enc    = (const int*)d_in[0];
    const int*   tgt    = (const int*)d_in[1];
    const float* emb    = (const float*)d_in[3];
    const float* W_att  = (const float*)d_in[4];
    const float* b_att  = (const float*)d_in[5];
    const float* W_comb = (const float*)d_in[6];
    const float* b_comb = (const float*)d_in[7];
    const float* W_ih   = (const float*)d_in[8];
    const float* b_ih   = (const float*)d_in[9];
    const float* W_hh   = (const float*)d_in[10];
    const float* b_hh   = (const float*)d_in[11];
    const float* W_fc   = (const float*)d_in[12];
    const float* b_fc   = (const float*)d_in[13];

    float* ws  = (float*)d_ws;
    float* out = (float*)d_out;
    f16* WCATM = (f16*)(ws + OFF_WCATM);
    f16* WATTM = (f16*)(ws + OFF_WATTM);
    f16* WFCPH = (f16*)(ws + OFF_WFCPH);

    hipLaunchKernelGGL(k_pe,      dim3(1),    dim3(128), 0, stream, ws + OFF_PE);
    hipLaunchKernelGGL(k_tr_att,  dim3(640),  dim3(256), 0, stream, W_att,  ws + OFF_WATT);
    hipLaunchKernelGGL(k_tr_comb, dim3(512),  dim3(256), 0, stream, W_comb, ws + OFF_WCOMBT);
    hipLaunchKernelGGL(k_p1b,     dim3(81),   dim3(320), 0, stream, emb, ws + OFF_WATT, b_att, ws + OFF_P1B);
    hipLaunchKernelGGL(k_p2q,     dim3(81),   dim3(256), 0, stream, emb, ws + OFF_WCOMBT, b_comb,
                       ws + OFF_P2B, ws + OFF_Q2T);
    hipLaunchKernelGGL(k_q2pe,    dim3(1),    dim3(256), 0, stream, ws + OFF_PE, ws + OFF_WCOMBT, ws + OFF_Q2PE);
    hipLaunchKernelGGL(k_pan_q2,  dim3(81),   dim3(256), 0, stream, ws + OFF_Q2T, ws + OFF_Q2TP);
    hipLaunchKernelGGL(k_pan_cat_m, dim3(2048), dim3(256), 0, stream, W_ih, W_hh, WCATM);
    hipLaunchKernelGGL(k_pan_att_m, dim3(320),  dim3(256), 0, stream, W_att, WATTM);
    hipLaunchKernelGGL(k_pan_fc_h,  dim3(81),   dim3(256), 0, stream, W_fc, WFCPH);

    hipLaunchKernelGGL(k_run, dim3(256), dim3(1024), 0, stream,
                       enc, tgt,
                       WATTM, ws + OFF_P1B, ws + OFF_P2B,
                       ws + OFF_Q2TP, ws + OFF_Q2PE, WCATM, WFCPH,
                       b_ih, b_hh, b_fc,
                       out, ws + OFF_LOSS);

    hipLaunchKernelGGL(k_final, dim3(1), dim3(256), 0, stream, ws + OFF_LOSS, out + (out_size - 1));
}